// Round 1
// baseline (438.803 us; speedup 1.0000x reference)
//
#include <hip/hip_runtime.h>

// QuantizedKVCache: the reference dequantizes the updated cache and then
// overwrites the fresh-token window with the exact fp values. Hence the
// quantization of the fresh tokens never reaches the output — the output is
//   out[s,h,:] = (cache[s,h,:] - zp[s,h]) * scale[s,h]   for s outside window
//   out[s,h,:] = val[s-pos,h,:]                          for s in [pos, pos+S_NEW)
// computed from the ORIGINAL cache/scales/zps inputs. Pure memory-bound copy.

// Fixed shapes from setup_inputs(): B=1, S_MAX=8192, H=32, D=128.
constexpr int H = 32;
constexpr int D = 128;
constexpr int HD4 = H * D / 4;   // float4 units per seq position = 1024
constexpr int D4_SHIFT = 5;      // D/4 = 32 -> token = idx >> 5

__global__ __launch_bounds__(256) void kv_dequant_kernel(
    const float4* __restrict__ val,    // (S_NEW, H, D) fp32
    const int4*  __restrict__ cache,   // (S_MAX, H, D) int32
    const float* __restrict__ scales,  // (S_MAX, H) fp32
    const int*   __restrict__ zps,     // (S_MAX, H) int32
    const int*   __restrict__ pos_ptr, // scalar input_pos on device
    float4* __restrict__ out,          // (S_MAX, H, D) fp32
    int n4,                            // total float4 units = S_MAX*H*D/4
    int nval4)                         // fresh float4 units  = S_NEW*H*D/4
{
    int idx = blockIdx.x * blockDim.x + threadIdx.x;
    if (idx >= n4) return;

    const int pos    = *pos_ptr;
    const int start4 = pos * HD4;

    if (idx >= start4 && idx < start4 + nval4) {
        // fresh tokens: exact fp passthrough (layout identical, just shifted)
        out[idx] = val[idx - start4];
    } else {
        const int token = idx >> D4_SHIFT;       // s*H + h
        const int4  c  = cache[idx];
        const float sc = scales[token];
        const float zp = (float)zps[token];
        float4 o;
        o.x = ((float)c.x - zp) * sc;
        o.y = ((float)c.y - zp) * sc;
        o.z = ((float)c.z - zp) * sc;
        o.w = ((float)c.w - zp) * sc;
        out[idx] = o;
    }
}

extern "C" void kernel_launch(void* const* d_in, const int* in_sizes, int n_in,
                              void* d_out, int out_size, void* d_ws, size_t ws_size,
                              hipStream_t stream) {
    const float* k_val   = (const float*)d_in[0];
    const float* v_val   = (const float*)d_in[1];
    const int*   k_cache = (const int*)d_in[2];
    const int*   v_cache = (const int*)d_in[3];
    const float* k_scale = (const float*)d_in[4];
    const float* v_scale = (const float*)d_in[5];
    const int*   k_zp    = (const int*)d_in[6];
    const int*   v_zp    = (const int*)d_in[7];
    const int*   pos     = (const int*)d_in[8];

    float* k_out = (float*)d_out;
    float* v_out = (float*)d_out + (out_size / 2);

    const int n4    = in_sizes[2] / 4;   // 8192*32*128/4 = 8,388,608
    const int nval4 = in_sizes[0] / 4;   // 128*32*128/4  =   524,288

    const int threads = 256;
    const int blocks  = (n4 + threads - 1) / threads;

    kv_dequant_kernel<<<blocks, threads, 0, stream>>>(
        (const float4*)k_val, (const int4*)k_cache, k_scale, k_zp, pos,
        (float4*)k_out, n4, nval4);
    kv_dequant_kernel<<<blocks, threads, 0, stream>>>(
        (const float4*)v_val, (const int4*)v_cache, v_scale, v_zp, pos,
        (float4*)v_out, n4, nval4);
}

// Round 2
// 432.674 us; speedup vs baseline: 1.0142x; 1.0142x over previous
//
#include <hip/hip_runtime.h>

// QuantizedKVCache: reference dequantizes the updated cache then overwrites
// the fresh-token window with exact fp values, so the output is
//   out[s,h,:] = (cache[s,h,:] - zp[s,h]) * scale[s,h]   (s outside window)
//   out[s,h,:] = val[s-pos,h,:]                          (s in [pos,pos+S_NEW))
// computed from the ORIGINAL inputs. Pure memory-bound stream:
// ~264 MiB read + 256 MiB write => roofline ~87 us at 6.3 TB/s.
//
// R1: fused single launch (k+v in one grid, wave-uniform split) +
// non-temporal load/store on the 512 MiB single-use streams.

// Fixed shapes: B=1, S_MAX=8192, H=32, D=128.
constexpr int HD4      = 32 * 128 / 4;  // float4 units per seq position = 1024
constexpr int D4_SHIFT = 5;             // D/4 = 32 -> token = idx >> 5

typedef int   iv4 __attribute__((ext_vector_type(4)));
typedef float fv4 __attribute__((ext_vector_type(4)));

__device__ __forceinline__ void dequant_one(
    const fv4* __restrict__ val,    // (S_NEW, H, D/4)
    const iv4* __restrict__ cache,  // (S_MAX, H, D/4)
    const float* __restrict__ scales,
    const int*   __restrict__ zps,
    fv4* __restrict__ out,
    int idx, int start4, int nval4)
{
    if (idx >= start4 && idx < start4 + nval4) {
        // fresh tokens: exact fp passthrough
        fv4 v = val[idx - start4];
        __builtin_nontemporal_store(v, &out[idx]);
    } else {
        const int token = idx >> D4_SHIFT;        // s*H + h
        iv4   c  = __builtin_nontemporal_load(&cache[idx]);
        float sc = scales[token];
        float zp = (float)zps[token];
        fv4 o;
        o.x = ((float)c.x - zp) * sc;
        o.y = ((float)c.y - zp) * sc;
        o.z = ((float)c.z - zp) * sc;
        o.w = ((float)c.w - zp) * sc;
        __builtin_nontemporal_store(o, &out[idx]);
    }
}

__global__ __launch_bounds__(256) void kv_dequant_fused(
    const fv4* __restrict__ k_val, const fv4* __restrict__ v_val,
    const iv4* __restrict__ k_cache, const iv4* __restrict__ v_cache,
    const float* __restrict__ k_scales, const float* __restrict__ v_scales,
    const int* __restrict__ k_zps, const int* __restrict__ v_zps,
    const int* __restrict__ pos_ptr,
    fv4* __restrict__ k_out, fv4* __restrict__ v_out,
    int n4, int nval4, int nblk_k)
{
    const int pos    = *pos_ptr;
    const int start4 = pos * HD4;

    if ((int)blockIdx.x < nblk_k) {
        int idx = blockIdx.x * blockDim.x + threadIdx.x;
        if (idx < n4)
            dequant_one(k_val, k_cache, k_scales, k_zps, k_out, idx, start4, nval4);
    } else {
        int idx = (blockIdx.x - nblk_k) * blockDim.x + threadIdx.x;
        if (idx < n4)
            dequant_one(v_val, v_cache, v_scales, v_zps, v_out, idx, start4, nval4);
    }
}

extern "C" void kernel_launch(void* const* d_in, const int* in_sizes, int n_in,
                              void* d_out, int out_size, void* d_ws, size_t ws_size,
                              hipStream_t stream) {
    const fv4*   k_val   = (const fv4*)d_in[0];
    const fv4*   v_val   = (const fv4*)d_in[1];
    const iv4*   k_cache = (const iv4*)d_in[2];
    const iv4*   v_cache = (const iv4*)d_in[3];
    const float* k_scale = (const float*)d_in[4];
    const float* v_scale = (const float*)d_in[5];
    const int*   k_zp    = (const int*)d_in[6];
    const int*   v_zp    = (const int*)d_in[7];
    const int*   pos     = (const int*)d_in[8];

    fv4* k_out = (fv4*)d_out;
    fv4* v_out = (fv4*)((float*)d_out + (out_size / 2));

    const int n4    = in_sizes[2] / 4;   // 8,388,608 float4 units per tensor
    const int nval4 = in_sizes[0] / 4;   //   524,288 fresh float4 units

    const int threads = 256;
    const int nblk_k  = (n4 + threads - 1) / threads;   // 32768
    const int blocks  = 2 * nblk_k;                     // 65536: k then v

    kv_dequant_fused<<<blocks, threads, 0, stream>>>(
        k_val, v_val, k_cache, v_cache, k_scale, v_scale, k_zp, v_zp, pos,
        k_out, v_out, n4, nval4, nblk_k);
}

// Round 3
// 430.316 us; speedup vs baseline: 1.0197x; 1.0055x over previous
//
#include <hip/hip_runtime.h>

// QuantizedKVCache: reference dequantizes the updated cache then overwrites
// the fresh-token window with exact fp values, so the output is
//   out[s,h,:] = (cache[s,h,:] - zp[s,h]) * scale[s,h]   (s outside window)
//   out[s,h,:] = val[s-pos,h,:]                          (s in [pos,pos+S_NEW))
// computed from the ORIGINAL inputs. Pure memory-bound stream:
// ~268 MiB read + 268 MiB write => roofline ~87 us at 6.3 TB/s.
//
// R2: block == seq position (uniform fresh/stale branch), 4 fv4/thread
// wave-strided for MLP, NT hints on the big streams.

// Fixed shapes: B=1, S_MAX=8192, H=32, D=128.
// fv4 units per seq position = H*D/4 = 1024; per token (s,h) = 32.

typedef int   iv4 __attribute__((ext_vector_type(4)));
typedef float fv4 __attribute__((ext_vector_type(4)));

__global__ __launch_bounds__(256) void kv_dequant_fused(
    const fv4* __restrict__ k_val, const fv4* __restrict__ v_val,
    const iv4* __restrict__ k_cache, const iv4* __restrict__ v_cache,
    const float* __restrict__ k_scales, const float* __restrict__ v_scales,
    const int* __restrict__ k_zps, const int* __restrict__ v_zps,
    const int* __restrict__ pos_ptr,
    fv4* __restrict__ k_out, fv4* __restrict__ v_out,
    int nblk,    // blocks per tensor = S_MAX = 8192
    int s_new)   // fresh seq positions = 128
{
    const int pos = *pos_ptr;

    int b = blockIdx.x;
    const fv4*   val;
    const iv4*   cache;
    const float* scales;
    const int*   zps;
    fv4*         out;
    if (b < nblk) {
        val = k_val; cache = k_cache; scales = k_scales; zps = k_zps; out = k_out;
    } else {
        b -= nblk;
        val = v_val; cache = v_cache; scales = v_scales; zps = v_zps; out = v_out;
    }

    const int t     = threadIdx.x;
    const int base4 = b << 10;          // fv4 index of this seq position
    const int rel   = b - pos;

    if (rel >= 0 && rel < s_new) {
        // fresh tokens: exact fp passthrough (block-uniform branch)
        const int vbase = rel << 10;
        #pragma unroll
        for (int j = 0; j < 4; ++j) {
            fv4 v = val[vbase + (j << 8) + t];
            __builtin_nontemporal_store(v, &out[base4 + (j << 8) + t]);
        }
    } else {
        iv4   c[4];
        float sc[4];
        float zp[4];
        #pragma unroll
        for (int j = 0; j < 4; ++j) {
            const int idx   = base4 + (j << 8) + t;
            const int token = idx >> 5;       // s*H + h
            c[j]  = __builtin_nontemporal_load(&cache[idx]);
            sc[j] = scales[token];
            zp[j] = (float)zps[token];
        }
        #pragma unroll
        for (int j = 0; j < 4; ++j) {
            fv4 o;
            o.x = ((float)c[j].x - zp[j]) * sc[j];
            o.y = ((float)c[j].y - zp[j]) * sc[j];
            o.z = ((float)c[j].z - zp[j]) * sc[j];
            o.w = ((float)c[j].w - zp[j]) * sc[j];
            __builtin_nontemporal_store(o, &out[base4 + (j << 8) + t]);
        }
    }
}

extern "C" void kernel_launch(void* const* d_in, const int* in_sizes, int n_in,
                              void* d_out, int out_size, void* d_ws, size_t ws_size,
                              hipStream_t stream) {
    const fv4*   k_val   = (const fv4*)d_in[0];
    const fv4*   v_val   = (const fv4*)d_in[1];
    const iv4*   k_cache = (const iv4*)d_in[2];
    const iv4*   v_cache = (const iv4*)d_in[3];
    const float* k_scale = (const float*)d_in[4];
    const float* v_scale = (const float*)d_in[5];
    const int*   k_zp    = (const int*)d_in[6];
    const int*   v_zp    = (const int*)d_in[7];
    const int*   pos     = (const int*)d_in[8];

    fv4* k_out = (fv4*)d_out;
    fv4* v_out = (fv4*)((float*)d_out + (out_size / 2));

    const int n4    = in_sizes[2] / 4;   // 8,388,608 fv4 per tensor
    const int nval4 = in_sizes[0] / 4;   //   131,072 fresh fv4
    const int nblk  = n4 >> 10;          // 8192 blocks per tensor (1 per seq pos)
    const int s_new = nval4 >> 10;       // 128 fresh seq positions

    kv_dequant_fused<<<2 * nblk, 256, 0, stream>>>(
        k_val, v_val, k_cache, v_cache, k_scale, v_scale, k_zp, v_zp, pos,
        k_out, v_out, nblk, s_new);
}